// Round 21
// baseline (104.368 us; speedup 1.0000x reference)
//
#include <hip/hip_runtime.h>
#include <hip/hip_bf16.h>

#define BATCH 64
#define NADJ  512
#define F     128
#define CROP0 128
#define CROP1 384
#define CN    256
#define BN_EPS 1e-5f

// Diagnosis round: rep-loops surface each kernel in rocprof top-5 with its
// own counters (fills occupy ~40us). Warm reps (L2-resident working set)
// separate HBM-latency vs structural (barrier/issue/VALU) theories.
#define KAREP 6
#define KBREP 20

typedef __attribute__((ext_vector_type(8))) short short8;
typedef __attribute__((ext_vector_type(4))) float f32x4;

__device__ __forceinline__ ushort f2bf(float x) {
  __hip_bfloat16 h = __float2bfloat16(x);  // RNE
  return *reinterpret_cast<ushort*>(&h);
}

__device__ __forceinline__ float bf2f(ushort u) {
  const unsigned v = (unsigned)u << 16;
  float f;
  __builtin_memcpy(&f, &v, 4);
  return f;
}

__device__ __forceinline__ short8 cvt8(const float4 a, const float4 b) {
  short8 r;
  r[0] = (short)f2bf(a.x); r[1] = (short)f2bf(a.y);
  r[2] = (short)f2bf(a.z); r[3] = (short)f2bf(a.w);
  r[4] = (short)f2bf(b.x); r[5] = (short)f2bf(b.y);
  r[6] = (short)f2bf(b.z); r[7] = (short)f2bf(b.w);
  return r;
}

// ---------------------------------------------------------------------------
// KA v18 body (R18 winner, 22.98us config), wrapped in KAREP idempotent reps.
// ---------------------------------------------------------------------------
__global__ __launch_bounds__(512, 1) void gcn_ka(
    const float* __restrict__ input, const float* __restrict__ adj,
    const float* __restrict__ W, const float* __restrict__ beta,
    float* __restrict__ out, ushort* __restrict__ Ocrop) {
  const int x = blockIdx.x & 7, y = blockIdx.x >> 3;
  const int b  = ((y >> 2) << 3) | x;  // batch
  const int qt = y & 3;                // quarter (64 n-rows)
  __shared__ ushort wt[128][136];      // W^T [f][i]
  __shared__ ushort ain[2][64][136];   // input chunk dbuf [m][i]
  __shared__ ushort stl[128][268];     // S^T full [f][m]
  const int tid = threadIdx.x;
  const int l = tid & 63, w = tid >> 6;
  const int lr = l & 15, lg = l >> 4;
  const int n0  = qt * 64 + (w & 3) * 16;
  const int wf0 = (w >> 2) * 64;
  const float* a0 =
      adj + ((size_t)b * NADJ + CROP0 + n0 + lr) * NADJ + CROP0;
  const float* inb = input + ((size_t)b * NADJ + CROP0) * F;
  const int msub = (w & 3) * 16;
  const int sf0  = (w >> 2) * 64;
  const int ml0  = tid >> 5;
  const int ic4  = (tid & 31) * 4;

  for (int rep = 0; rep < KAREP; ++rep) {
    asm volatile("" ::: "memory");
    __syncthreads();

    // ---- pre-issue agg A-operand: 16 x float4 of adj ----
    float4 xreg[16];
#pragma unroll
    for (int ks = 0; ks < 8; ++ks) {
      const int k0 = ks * 32 + lg * 8;
      xreg[2 * ks]     = *reinterpret_cast<const float4*>(&a0[k0]);
      xreg[2 * ks + 1] = *reinterpret_cast<const float4*>(&a0[k0 + 4]);
    }

    // ---- beta-fill non-crop rows of out ----
    {
      const int gid = blockIdx.x * 512 + tid;
#pragma unroll
      for (int q = 0; q < 4; ++q) {
        const int g2 = gid + q * 131072;
        const int c4 = (g2 & 31) * 4;
        const int rr = (g2 >> 5) & 255;
        const int bb = g2 >> 13;
        const int n  = rr < 128 ? rr : rr + 256;
        const float4 bv =
            *reinterpret_cast<const float4*>(&beta[(size_t)n * F + c4]);
        *reinterpret_cast<float4*>(&out[((size_t)bb * NADJ + n) * F + c4]) =
            bv;
      }
    }

    // ---- stage W^T ----
    {
      const int i0 = tid & 63;
      const int fq = (tid >> 6) * 16;
#pragma unroll
      for (int ih = 0; ih < 2; ++ih) {
        const int i = i0 + ih * 64;
        const float* wr = &W[(size_t)i * F + fq];
        float4 v[4];
#pragma unroll
        for (int q = 0; q < 4; ++q)
          v[q] = reinterpret_cast<const float4*>(wr)[q];
#pragma unroll
        for (int q = 0; q < 4; ++q) {
          wt[fq + q * 4 + 0][i] = f2bf(v[q].x);
          wt[fq + q * 4 + 1][i] = f2bf(v[q].y);
          wt[fq + q * 4 + 2][i] = f2bf(v[q].z);
          wt[fq + q * 4 + 3][i] = f2bf(v[q].w);
        }
      }
    }

    // ---- chunk-0 prefetch + adj cvt in shadow ----
    float4 pv[4];
#pragma unroll
    for (int q = 0; q < 4; ++q)
      pv[q] = *reinterpret_cast<const float4*>(
          &inb[(size_t)(ml0 + q * 16) * F + ic4]);

    short8 areg[8];
#pragma unroll
    for (int ks = 0; ks < 8; ++ks)
      areg[ks] = cvt8(xreg[2 * ks], xreg[2 * ks + 1]);

#pragma unroll
    for (int q = 0; q < 4; ++q)
      *reinterpret_cast<ushort4*>(&ain[0][ml0 + q * 16][ic4]) =
          make_ushort4(f2bf(pv[q].x), f2bf(pv[q].y), f2bf(pv[q].z),
                       f2bf(pv[q].w));
    __syncthreads();  // ain[0] + wt visible

    // ---- S-chunks + interleaved agg; 1 barrier/chunk ----
    f32x4 acc[4] = {};
#pragma unroll
    for (int cc = 0; cc < 4; ++cc) {
      const int mc = cc * 64;
      if (cc < 3) {
#pragma unroll
        for (int q = 0; q < 4; ++q)
          pv[q] = *reinterpret_cast<const float4*>(
              &inb[(size_t)(mc + 64 + ml0 + q * 16) * F + ic4]);
      }
      if (cc > 0) {
        const int kb0 = mc - 64;
#pragma unroll
        for (int ks2 = 0; ks2 < 2; ++ks2) {
          const int ks = (cc - 1) * 2 + ks2;
          const int k0 = kb0 + ks2 * 32 + lg * 8;
#pragma unroll
          for (int fi = 0; fi < 4; ++fi) {
            const short8 bv = *reinterpret_cast<const short8*>(
                &stl[wf0 + fi * 16 + lr][k0]);
            acc[fi] = __builtin_amdgcn_mfma_f32_16x16x32_bf16(
                areg[ks], bv, acc[fi], 0, 0, 0);
          }
        }
      }
      f32x4 sacc[4] = {};
#pragma unroll
      for (int ks = 0; ks < 4; ++ks) {
        const int k0 = ks * 32 + lg * 8;
        const short8 av =
            *reinterpret_cast<const short8*>(&ain[cc & 1][msub + lr][k0]);
#pragma unroll
        for (int fi = 0; fi < 4; ++fi) {
          const short8 bv =
              *reinterpret_cast<const short8*>(&wt[sf0 + fi * 16 + lr][k0]);
          sacc[fi] = __builtin_amdgcn_mfma_f32_16x16x32_bf16(av, bv, sacc[fi],
                                                             0, 0, 0);
        }
      }
#pragma unroll
      for (int fi = 0; fi < 4; ++fi)
        *reinterpret_cast<ushort4*>(
            &stl[sf0 + fi * 16 + lr][mc + msub + lg * 4]) =
            make_ushort4(f2bf(sacc[fi][0]), f2bf(sacc[fi][1]),
                         f2bf(sacc[fi][2]), f2bf(sacc[fi][3]));
      if (cc < 3) {
#pragma unroll
        for (int q = 0; q < 4; ++q)
          *reinterpret_cast<ushort4*>(
              &ain[(cc + 1) & 1][ml0 + q * 16][ic4]) =
              make_ushort4(f2bf(pv[q].x), f2bf(pv[q].y), f2bf(pv[q].z),
                           f2bf(pv[q].w));
      }
      __syncthreads();
    }

    // ---- final agg chunk ----
#pragma unroll
    for (int ks2 = 0; ks2 < 2; ++ks2) {
      const int ks = 6 + ks2;
      const int k0 = 192 + ks2 * 32 + lg * 8;
#pragma unroll
      for (int fi = 0; fi < 4; ++fi) {
        const short8 bv =
            *reinterpret_cast<const short8*>(&stl[wf0 + fi * 16 + lr][k0]);
        acc[fi] = __builtin_amdgcn_mfma_f32_16x16x32_bf16(areg[ks], bv,
                                                          acc[fi], 0, 0, 0);
      }
    }

    // ---- store Ocrop (bf16) ----
#pragma unroll
    for (int fi = 0; fi < 4; ++fi) {
      const int f = wf0 + fi * 16 + lr;
      const int n = n0 + lg * 4;
#pragma unroll
      for (int r = 0; r < 4; ++r)
        Ocrop[((size_t)b * CN + n + r) * F + f] = f2bf(acc[fi][r]);
    }
  }
}

// ---------------------------------------------------------------------------
// KB v19 body (vectorized x4), wrapped in KBREP idempotent reps.
// ---------------------------------------------------------------------------
__global__ __launch_bounds__(256) void gcn_kb(
    const ushort* __restrict__ Ocrop, float* __restrict__ out,
    const float* __restrict__ gamma, const float* __restrict__ beta) {
  __shared__ f32x4 s_l[256], s2_l[256];
  __shared__ f32x4 m_l[32], r_l[32];
  const int tid = threadIdx.x;
  const int qq = tid & 31, bg = tid >> 5;
  const int j  = (blockIdx.x * 32 + qq) * 4;
  const int nl = j >> 7, f = j & 127;
  const int nf = (CROP0 + nl) * F + f;
  const ushort* p = Ocrop + (size_t)j + (size_t)bg * 8 * CN * F;

  for (int rep = 0; rep < KBREP; ++rep) {
    asm volatile("" ::: "memory");
    __syncthreads();
    f32x4 xv[8];
    f32x4 s = {0.f, 0.f, 0.f, 0.f}, s2 = {0.f, 0.f, 0.f, 0.f};
#pragma unroll
    for (int bb = 0; bb < 8; ++bb) {
      const ushort4 u =
          *reinterpret_cast<const ushort4*>(&p[(size_t)bb * CN * F]);
      f32x4 v;
      v[0] = bf2f(u.x); v[1] = bf2f(u.y); v[2] = bf2f(u.z); v[3] = bf2f(u.w);
      xv[bb] = v;
      s += v;
      s2 += v * v;
    }
    s_l[tid]  = s;
    s2_l[tid] = s2;
    __syncthreads();
    if (tid < 32) {
      f32x4 ts = {0.f, 0.f, 0.f, 0.f}, ts2 = {0.f, 0.f, 0.f, 0.f};
#pragma unroll
      for (int g = 0; g < 8; ++g) {
        ts += s_l[g * 32 + tid];
        ts2 += s2_l[g * 32 + tid];
      }
      const f32x4 mean = ts * (1.f / BATCH);
      const f32x4 var  = ts2 * (1.f / BATCH) - mean * mean;
      f32x4 rs;
      rs[0] = rsqrtf(var[0] + BN_EPS);
      rs[1] = rsqrtf(var[1] + BN_EPS);
      rs[2] = rsqrtf(var[2] + BN_EPS);
      rs[3] = rsqrtf(var[3] + BN_EPS);
      m_l[tid] = mean;
      r_l[tid] = rs;
    }
    __syncthreads();
    const f32x4 mean = m_l[qq];
    const f32x4 rs   = r_l[qq];
    const float4 gm = *reinterpret_cast<const float4*>(&gamma[nf]);
    const float4 bt = *reinterpret_cast<const float4*>(&beta[nf]);
    f32x4 a, c;
    a[0] = rs[0] * gm.x; a[1] = rs[1] * gm.y;
    a[2] = rs[2] * gm.z; a[3] = rs[3] * gm.w;
    c[0] = bt.x - mean[0] * a[0]; c[1] = bt.y - mean[1] * a[1];
    c[2] = bt.z - mean[2] * a[2]; c[3] = bt.w - mean[3] * a[3];
#pragma unroll
    for (int bb = 0; bb < 8; ++bb) {
      const f32x4 yv = xv[bb] * a + c;
      *reinterpret_cast<f32x4*>(
          &out[(size_t)nf + (size_t)(bg * 8 + bb) * NADJ * F]) = yv;
    }
  }
}

extern "C" void kernel_launch(void* const* d_in, const int* in_sizes, int n_in,
                              void* d_out, int out_size, void* d_ws,
                              size_t ws_size, hipStream_t stream) {
  const float* input = (const float*)d_in[0];
  const float* adj   = (const float*)d_in[1];
  const float* W     = (const float*)d_in[2];
  const float* gamma = (const float*)d_in[3];
  const float* beta  = (const float*)d_in[4];
  float* out = (float*)d_out;

  ushort* Ocrop = (ushort*)d_ws;  // 4.2 MB

  gcn_ka<<<256, 512, 0, stream>>>(input, adj, W, beta, out, Ocrop);
  gcn_kb<<<256, 256, 0, stream>>>(Ocrop, out, gamma, beta);
}

// Round 22
// 22.225 us; speedup vs baseline: 4.6960x; 4.6960x over previous
//
#include <hip/hip_runtime.h>
#include <hip/hip_bf16.h>

#define BATCH 64
#define NADJ  512
#define F     128
#define CROP0 128
#define CROP1 384
#define CN    256
#define BN_EPS 1e-5f

typedef __attribute__((ext_vector_type(8))) short short8;
typedef __attribute__((ext_vector_type(4))) float f32x4;

__device__ __forceinline__ ushort f2bf(float x) {
  __hip_bfloat16 h = __float2bfloat16(x);  // RNE
  return *reinterpret_cast<ushort*>(&h);
}

__device__ __forceinline__ float bf2f(ushort u) {
  const unsigned v = (unsigned)u << 16;
  float f;
  __builtin_memcpy(&f, &v, 4);
  return f;
}

__device__ __forceinline__ short8 cvt8(const float4 a, const float4 b) {
  short8 r;
  r[0] = (short)f2bf(a.x); r[1] = (short)f2bf(a.y);
  r[2] = (short)f2bf(a.z); r[3] = (short)f2bf(a.w);
  r[4] = (short)f2bf(b.x); r[5] = (short)f2bf(b.y);
  r[6] = (short)f2bf(b.z); r[7] = (short)f2bf(b.w);
  return r;
}

// Relaxed barrier: publish this wave's LDS writes (lgkmcnt only), then
// s_barrier — WITHOUT the vmcnt(0) drain __syncthreads() emits. Prefetched
// global loads stay in flight across the barrier (T4 principle).
__device__ __forceinline__ void bar_lds() {
  asm volatile("s_waitcnt lgkmcnt(0)" ::: "memory");
  __builtin_amdgcn_s_barrier();
  asm volatile("" ::: "memory");
}

// ---------------------------------------------------------------------------
// KA v22 = R18 math + (1) relaxed barriers (no vmcnt drain), (2) in-order-
// vmcnt-aware issue order: W -> input c0,c1 -> adj slices 0,1 -> beta;
// adj slices 2,3 issued in bodies 0,1; lazy cvt at use. Beta-fill stores
// stream right after barrier 1 (during S-phase).
// 256 blocks x 512 threads, 1 block/CU; block=(b,qt), 4 blocks/batch on
// XCD (b&7). LDS: wt 34816 + ain 2x17408 + stl 68608 = 138240 B.
// ---------------------------------------------------------------------------
#define IN_PREFETCH(PV, CHUNK)                                              \
  _Pragma("unroll") for (int q = 0; q < 4; ++q)                             \
      PV[q] = *reinterpret_cast<const float4*>(                             \
          &inb[(size_t)((CHUNK) * 64 + ml0 + q * 16) * F + ic4]);

#define ADJ_SLICE(SX, C)                                                    \
  _Pragma("unroll") for (int t = 0; t < 4; ++t)                             \
      SX[t] = *reinterpret_cast<const float4*>(                             \
          &a0[(C) * 64 + (t >> 1) * 32 + lg * 8 + (t & 1) * 4]);

#define AIN_WRITE(BUF, PV)                                                  \
  _Pragma("unroll") for (int q = 0; q < 4; ++q)                             \
      *reinterpret_cast<ushort4*>(&ain[BUF][ml0 + q * 16][ic4]) =           \
          make_ushort4(f2bf(PV[q].x), f2bf(PV[q].y), f2bf(PV[q].z),         \
                       f2bf(PV[q].w));

#define S_CHUNK(CC)                                                         \
  {                                                                         \
    f32x4 sacc[4] = {};                                                     \
    _Pragma("unroll") for (int ks = 0; ks < 4; ++ks) {                      \
      const int k0 = ks * 32 + lg * 8;                                      \
      const short8 av =                                                     \
          *reinterpret_cast<const short8*>(&ain[(CC) & 1][msub + lr][k0]);  \
      _Pragma("unroll") for (int fi = 0; fi < 4; ++fi) {                    \
        const short8 bv =                                                   \
            *reinterpret_cast<const short8*>(&wt[sf0 + fi * 16 + lr][k0]);  \
        sacc[fi] = __builtin_amdgcn_mfma_f32_16x16x32_bf16(av, bv,          \
                                                           sacc[fi], 0, 0,  \
                                                           0);              \
      }                                                                     \
    }                                                                       \
    _Pragma("unroll") for (int fi = 0; fi < 4; ++fi)                        \
        *reinterpret_cast<ushort4*>(                                        \
            &stl[sf0 + fi * 16 + lr][(CC) * 64 + msub + lg * 4]) =          \
            make_ushort4(f2bf(sacc[fi][0]), f2bf(sacc[fi][1]),              \
                         f2bf(sacc[fi][2]), f2bf(sacc[fi][3]));             \
  }

#define AGG_SLICE(SX, C)                                                    \
  _Pragma("unroll") for (int ks2 = 0; ks2 < 2; ++ks2) {                     \
    const int k0 = (C) * 64 + ks2 * 32 + lg * 8;                            \
    const short8 av = cvt8(SX[2 * ks2], SX[2 * ks2 + 1]);                   \
    _Pragma("unroll") for (int fi = 0; fi < 4; ++fi) {                      \
      const short8 bv =                                                     \
          *reinterpret_cast<const short8*>(&stl[wf0 + fi * 16 + lr][k0]);   \
      acc[fi] = __builtin_amdgcn_mfma_f32_16x16x32_bf16(av, bv, acc[fi],    \
                                                        0, 0, 0);           \
    }                                                                       \
  }

__global__ __launch_bounds__(512, 1) void gcn_ka(
    const float* __restrict__ input, const float* __restrict__ adj,
    const float* __restrict__ W, const float* __restrict__ beta,
    float* __restrict__ out, ushort* __restrict__ Ocrop) {
  const int x = blockIdx.x & 7, y = blockIdx.x >> 3;
  const int b  = ((y >> 2) << 3) | x;  // batch
  const int qt = y & 3;                // quarter (64 n-rows)
  __shared__ ushort wt[128][136];      // W^T [f][i]
  __shared__ ushort ain[2][64][136];   // input chunk dbuf [m][i]
  __shared__ ushort stl[128][268];     // S^T full [f][m]
  const int tid = threadIdx.x;
  const int l = tid & 63, w = tid >> 6;
  const int lr = l & 15, lg = l >> 4;
  const int n0   = qt * 64 + (w & 3) * 16;
  const int wf0  = (w >> 2) * 64;
  const int msub = (w & 3) * 16;
  const int sf0  = (w >> 2) * 64;
  const int ml0  = tid >> 5;
  const int ic4  = (tid & 31) * 4;
  const float* inb = input + ((size_t)b * NADJ + CROP0) * F;
  const float* a0 =
      adj + ((size_t)b * NADJ + CROP0 + n0 + lr) * NADJ + CROP0;

  // ---- issue order: W (critical) ----
  const int i0 = tid & 63;
  const int fq = (tid >> 6) * 16;
  float4 wv[8];
#pragma unroll
  for (int ih = 0; ih < 2; ++ih) {
    const float* wr = &W[(size_t)(i0 + ih * 64) * F + fq];
#pragma unroll
    for (int q = 0; q < 4; ++q)
      wv[ih * 4 + q] = reinterpret_cast<const float4*>(wr)[q];
  }
  // ---- input chunks 0,1 ----
  float4 pv[4], pv2[4];
  IN_PREFETCH(pv, 0)
  IN_PREFETCH(pv2, 1)
  // ---- adj slices 0,1 (stream; consumed bodies 1,2) ----
  float4 sA[4], sB[4], sC[4], sD[4];
  ADJ_SLICE(sA, 0)
  ADJ_SLICE(sB, 1)
  // ---- beta loads (stores after barrier 1) ----
  float4 btv[4];
  int bidx[4];
#pragma unroll
  for (int q = 0; q < 4; ++q) {
    const int g2 = blockIdx.x * 512 + tid + q * 131072;
    const int c4 = (g2 & 31) * 4;
    const int rr = (g2 >> 5) & 255;
    const int bb = g2 >> 13;
    const int n  = rr < 128 ? rr : rr + 256;
    btv[q]  = *reinterpret_cast<const float4*>(&beta[(size_t)n * F + c4]);
    bidx[q] = ((bb * NADJ + n) << 7) + c4;
  }

  // ---- wt writes (waits W only; later streams stay in flight) ----
#pragma unroll
  for (int ih = 0; ih < 2; ++ih) {
    const int i = i0 + ih * 64;
#pragma unroll
    for (int q = 0; q < 4; ++q) {
      wt[fq + q * 4 + 0][i] = f2bf(wv[ih * 4 + q].x);
      wt[fq + q * 4 + 1][i] = f2bf(wv[ih * 4 + q].y);
      wt[fq + q * 4 + 2][i] = f2bf(wv[ih * 4 + q].z);
      wt[fq + q * 4 + 3][i] = f2bf(wv[ih * 4 + q].w);
    }
  }
  // ---- ain[0] writes (waits input c0 only) ----
  AIN_WRITE(0, pv)
  bar_lds();

  // ---- beta-fill stores: stream during S-phase ----
#pragma unroll
  for (int q = 0; q < 4; ++q)
    *reinterpret_cast<float4*>(&out[(size_t)bidx[q]]) = btv[q];

  f32x4 acc[4] = {};
  // body 0: chunk0 S-compute; stage chunk1; issue slice2 + input c2
  ADJ_SLICE(sC, 2)
  IN_PREFETCH(pv, 2)
  S_CHUNK(0)
  AIN_WRITE(1, pv2)
  bar_lds();
  // body 1: agg slice0; chunk1 S; stage chunk2; issue slice3 + input c3
  ADJ_SLICE(sD, 3)
  IN_PREFETCH(pv2, 3)
  AGG_SLICE(sA, 0)
  S_CHUNK(1)
  AIN_WRITE(0, pv)
  bar_lds();
  // body 2: agg slice1; chunk2 S; stage chunk3
  AGG_SLICE(sB, 1)
  S_CHUNK(2)
  AIN_WRITE(1, pv2)
  bar_lds();
  // body 3: agg slice2; chunk3 S
  AGG_SLICE(sC, 2)
  S_CHUNK(3)
  bar_lds();
  // final: agg slice3
  AGG_SLICE(sD, 3)

  // ---- store Ocrop (bf16): col(f)=lane&15, row(n)=4*lg+reg ----
#pragma unroll
  for (int fi = 0; fi < 4; ++fi) {
    const int f = wf0 + fi * 16 + lr;
    const int n = n0 + lg * 4;
#pragma unroll
    for (int r = 0; r < 4; ++r)
      Ocrop[((size_t)b * CN + n + r) * F + f] = f2bf(acc[fi][r]);
  }
}

// ---------------------------------------------------------------------------
// KB: BN stats + normalize crop rows (vectorized x4; bf16 in, fp32 out).
// ---------------------------------------------------------------------------
__global__ __launch_bounds__(256) void gcn_kb(
    const ushort* __restrict__ Ocrop, float* __restrict__ out,
    const float* __restrict__ gamma, const float* __restrict__ beta) {
  __shared__ f32x4 s_l[256], s2_l[256];
  __shared__ f32x4 m_l[32], r_l[32];
  const int tid = threadIdx.x;
  const int qq = tid & 31, bg = tid >> 5;
  const int j  = (blockIdx.x * 32 + qq) * 4;
  const int nl = j >> 7, f = j & 127;
  const int nf = (CROP0 + nl) * F + f;
  const ushort* p = Ocrop + (size_t)j + (size_t)bg * 8 * CN * F;

  f32x4 xv[8];
  f32x4 s = {0.f, 0.f, 0.f, 0.f}, s2 = {0.f, 0.f, 0.f, 0.f};
#pragma unroll
  for (int bb = 0; bb < 8; ++bb) {
    const ushort4 u =
        *reinterpret_cast<const ushort4*>(&p[(size_t)bb * CN * F]);
    f32x4 v;
    v[0] = bf2f(u.x); v[1] = bf2f(u.y); v[2] = bf2f(u.z); v[3] = bf2f(u.w);
    xv[bb] = v;
    s += v;
    s2 += v * v;
  }
  s_l[tid]  = s;
  s2_l[tid] = s2;
  __syncthreads();
  if (tid < 32) {
    f32x4 ts = {0.f, 0.f, 0.f, 0.f}, ts2 = {0.f, 0.f, 0.f, 0.f};
#pragma unroll
    for (int g = 0; g < 8; ++g) {
      ts += s_l[g * 32 + tid];
      ts2 += s2_l[g * 32 + tid];
    }
    const f32x4 mean = ts * (1.f / BATCH);
    const f32x4 var  = ts2 * (1.f / BATCH) - mean * mean;
    f32x4 rs;
    rs[0] = rsqrtf(var[0] + BN_EPS);
    rs[1] = rsqrtf(var[1] + BN_EPS);
    rs[2] = rsqrtf(var[2] + BN_EPS);
    rs[3] = rsqrtf(var[3] + BN_EPS);
    m_l[tid] = mean;
    r_l[tid] = rs;
  }
  __syncthreads();
  const f32x4 mean = m_l[qq];
  const f32x4 rs   = r_l[qq];
  const float4 gm = *reinterpret_cast<const float4*>(&gamma[nf]);
  const float4 bt = *reinterpret_cast<const float4*>(&beta[nf]);
  f32x4 a, c;
  a[0] = rs[0] * gm.x; a[1] = rs[1] * gm.y;
  a[2] = rs[2] * gm.z; a[3] = rs[3] * gm.w;
  c[0] = bt.x - mean[0] * a[0]; c[1] = bt.y - mean[1] * a[1];
  c[2] = bt.z - mean[2] * a[2]; c[3] = bt.w - mean[3] * a[3];
#pragma unroll
  for (int bb = 0; bb < 8; ++bb) {
    const f32x4 yv = xv[bb] * a + c;
    *reinterpret_cast<f32x4*>(
        &out[(size_t)nf + (size_t)(bg * 8 + bb) * NADJ * F]) = yv;
  }
}

extern "C" void kernel_launch(void* const* d_in, const int* in_sizes, int n_in,
                              void* d_out, int out_size, void* d_ws,
                              size_t ws_size, hipStream_t stream) {
  const float* input = (const float*)d_in[0];
  const float* adj   = (const float*)d_in[1];
  const float* W     = (const float*)d_in[2];
  const float* gamma = (const float*)d_in[3];
  const float* beta  = (const float*)d_in[4];
  float* out = (float*)d_out;

  ushort* Ocrop = (ushort*)d_ws;  // 64*256*128 bf16 = 4.2 MB

  gcn_ka<<<256, 512, 0, stream>>>(input, adj, W, beta, out, Ocrop);
  gcn_kb<<<256, 256, 0, stream>>>(Ocrop, out, gamma, beta);
}

// Round 23
// 21.721 us; speedup vs baseline: 4.8049x; 1.0232x over previous
//
#include <hip/hip_runtime.h>
#include <hip/hip_bf16.h>

#define BATCH 64
#define NADJ  512
#define F     128
#define CROP0 128
#define CROP1 384
#define CN    256
#define BN_EPS 1e-5f

typedef __attribute__((ext_vector_type(8))) short short8;
typedef __attribute__((ext_vector_type(4))) float f32x4;

__device__ __forceinline__ ushort f2bf(float x) {
  __hip_bfloat16 h = __float2bfloat16(x);  // RNE
  return *reinterpret_cast<ushort*>(&h);
}

__device__ __forceinline__ float bf2f(ushort u) {
  const unsigned v = (unsigned)u << 16;
  float f;
  __builtin_memcpy(&f, &v, 4);
  return f;
}

__device__ __forceinline__ short8 cvt8(const float4 a, const float4 b) {
  short8 r;
  r[0] = (short)f2bf(a.x); r[1] = (short)f2bf(a.y);
  r[2] = (short)f2bf(a.z); r[3] = (short)f2bf(a.w);
  r[4] = (short)f2bf(b.x); r[5] = (short)f2bf(b.y);
  r[6] = (short)f2bf(b.z); r[7] = (short)f2bf(b.w);
  return r;
}

// Relaxed barrier: publish LDS writes (lgkmcnt only) + s_barrier, WITHOUT
// the vmcnt(0) drain __syncthreads() emits — prefetches stay in flight.
__device__ __forceinline__ void bar_lds() {
  asm volatile("s_waitcnt lgkmcnt(0)" ::: "memory");
  __builtin_amdgcn_s_barrier();
  asm volatile("" ::: "memory");
}

// ---------------------------------------------------------------------------
// KA v23 = R22 + W^T fragments hoisted to registers once (wreg[16] short8):
// S-phase B-operand LDS reads drop 4x (64 -> 16 ds_read_b128 per wave), and
// 48 lgkm waits leave the barrier-locked bodies. Everything else identical.
// ---------------------------------------------------------------------------
#define IN_PREFETCH(PV, CHUNK)                                              \
  _Pragma("unroll") for (int q = 0; q < 4; ++q)                             \
      PV[q] = *reinterpret_cast<const float4*>(                             \
          &inb[(size_t)((CHUNK) * 64 + ml0 + q * 16) * F + ic4]);

#define ADJ_SLICE(SX, C)                                                    \
  _Pragma("unroll") for (int t = 0; t < 4; ++t)                             \
      SX[t] = *reinterpret_cast<const float4*>(                             \
          &a0[(C) * 64 + (t >> 1) * 32 + lg * 8 + (t & 1) * 4]);

#define AIN_WRITE(BUF, PV)                                                  \
  _Pragma("unroll") for (int q = 0; q < 4; ++q)                             \
      *reinterpret_cast<ushort4*>(&ain[BUF][ml0 + q * 16][ic4]) =           \
          make_ushort4(f2bf(PV[q].x), f2bf(PV[q].y), f2bf(PV[q].z),         \
                       f2bf(PV[q].w));

#define S_CHUNK(CC)                                                         \
  {                                                                         \
    f32x4 sacc[4] = {};                                                     \
    _Pragma("unroll") for (int ks = 0; ks < 4; ++ks) {                      \
      const int k0 = ks * 32 + lg * 8;                                      \
      const short8 av =                                                     \
          *reinterpret_cast<const short8*>(&ain[(CC) & 1][msub + lr][k0]);  \
      _Pragma("unroll") for (int fi = 0; fi < 4; ++fi) {                    \
        sacc[fi] = __builtin_amdgcn_mfma_f32_16x16x32_bf16(                 \
            av, wreg[ks * 4 + fi], sacc[fi], 0, 0, 0);                      \
      }                                                                     \
    }                                                                       \
    _Pragma("unroll") for (int fi = 0; fi < 4; ++fi)                        \
        *reinterpret_cast<ushort4*>(                                        \
            &stl[sf0 + fi * 16 + lr][(CC) * 64 + msub + lg * 4]) =          \
            make_ushort4(f2bf(sacc[fi][0]), f2bf(sacc[fi][1]),              \
                         f2bf(sacc[fi][2]), f2bf(sacc[fi][3]));             \
  }

#define AGG_SLICE(SX, C)                                                    \
  _Pragma("unroll") for (int ks2 = 0; ks2 < 2; ++ks2) {                     \
    const int k0 = (C) * 64 + ks2 * 32 + lg * 8;                            \
    const short8 av = cvt8(SX[2 * ks2], SX[2 * ks2 + 1]);                   \
    _Pragma("unroll") for (int fi = 0; fi < 4; ++fi) {                      \
      const short8 bv =                                                     \
          *reinterpret_cast<const short8*>(&stl[wf0 + fi * 16 + lr][k0]);   \
      acc[fi] = __builtin_amdgcn_mfma_f32_16x16x32_bf16(av, bv, acc[fi],    \
                                                        0, 0, 0);           \
    }                                                                       \
  }

__global__ __launch_bounds__(512, 1) void gcn_ka(
    const float* __restrict__ input, const float* __restrict__ adj,
    const float* __restrict__ W, const float* __restrict__ beta,
    float* __restrict__ out, ushort* __restrict__ Ocrop) {
  const int x = blockIdx.x & 7, y = blockIdx.x >> 3;
  const int b  = ((y >> 2) << 3) | x;  // batch
  const int qt = y & 3;                // quarter (64 n-rows)
  __shared__ ushort wt[128][136];      // W^T [f][i]
  __shared__ ushort ain[2][64][136];   // input chunk dbuf [m][i]
  __shared__ ushort stl[128][268];     // S^T full [f][m]
  const int tid = threadIdx.x;
  const int l = tid & 63, w = tid >> 6;
  const int lr = l & 15, lg = l >> 4;
  const int n0   = qt * 64 + (w & 3) * 16;
  const int wf0  = (w >> 2) * 64;
  const int msub = (w & 3) * 16;
  const int sf0  = (w >> 2) * 64;
  const int ml0  = tid >> 5;
  const int ic4  = (tid & 31) * 4;
  const float* inb = input + ((size_t)b * NADJ + CROP0) * F;
  const float* a0 =
      adj + ((size_t)b * NADJ + CROP0 + n0 + lr) * NADJ + CROP0;

  // ---- issue order: W (critical) ----
  const int i0 = tid & 63;
  const int fq = (tid >> 6) * 16;
  float4 wv[8];
#pragma unroll
  for (int ih = 0; ih < 2; ++ih) {
    const float* wr = &W[(size_t)(i0 + ih * 64) * F + fq];
#pragma unroll
    for (int q = 0; q < 4; ++q)
      wv[ih * 4 + q] = reinterpret_cast<const float4*>(wr)[q];
  }
  // ---- input chunks 0,1 ----
  float4 pv[4], pv2[4];
  IN_PREFETCH(pv, 0)
  IN_PREFETCH(pv2, 1)
  // ---- adj slices 0,1 ----
  float4 sA[4], sB[4], sC[4], sD[4];
  ADJ_SLICE(sA, 0)
  ADJ_SLICE(sB, 1)
  // ---- beta loads ----
  float4 btv[4];
  int bidx[4];
#pragma unroll
  for (int q = 0; q < 4; ++q) {
    const int g2 = blockIdx.x * 512 + tid + q * 131072;
    const int c4 = (g2 & 31) * 4;
    const int rr = (g2 >> 5) & 255;
    const int bb = g2 >> 13;
    const int n  = rr < 128 ? rr : rr + 256;
    btv[q]  = *reinterpret_cast<const float4*>(&beta[(size_t)n * F + c4]);
    bidx[q] = ((bb * NADJ + n) << 7) + c4;
  }

  // ---- wt writes (waits W only) ----
#pragma unroll
  for (int ih = 0; ih < 2; ++ih) {
    const int i = i0 + ih * 64;
#pragma unroll
    for (int q = 0; q < 4; ++q) {
      wt[fq + q * 4 + 0][i] = f2bf(wv[ih * 4 + q].x);
      wt[fq + q * 4 + 1][i] = f2bf(wv[ih * 4 + q].y);
      wt[fq + q * 4 + 2][i] = f2bf(wv[ih * 4 + q].z);
      wt[fq + q * 4 + 3][i] = f2bf(wv[ih * 4 + q].w);
    }
  }
  // ---- ain[0] writes (waits input c0 only) ----
  AIN_WRITE(0, pv)
  bar_lds();

  // ---- beta-fill stores: stream during S-phase ----
#pragma unroll
  for (int q = 0; q < 4; ++q)
    *reinterpret_cast<float4*>(&out[(size_t)bidx[q]]) = btv[q];

  // ---- hoist W^T fragments to registers ONCE (16 b128 reads) ----
  short8 wreg[16];
#pragma unroll
  for (int ks = 0; ks < 4; ++ks)
#pragma unroll
    for (int fi = 0; fi < 4; ++fi)
      wreg[ks * 4 + fi] = *reinterpret_cast<const short8*>(
          &wt[sf0 + fi * 16 + lr][ks * 32 + lg * 8]);

  f32x4 acc[4] = {};
  // body 0: chunk0 S; stage chunk1; issue slice2 + input c2
  ADJ_SLICE(sC, 2)
  IN_PREFETCH(pv, 2)
  S_CHUNK(0)
  AIN_WRITE(1, pv2)
  bar_lds();
  // body 1: agg slice0; chunk1 S; stage chunk2; issue slice3 + input c3
  ADJ_SLICE(sD, 3)
  IN_PREFETCH(pv2, 3)
  AGG_SLICE(sA, 0)
  S_CHUNK(1)
  AIN_WRITE(0, pv)
  bar_lds();
  // body 2: agg slice1; chunk2 S; stage chunk3
  AGG_SLICE(sB, 1)
  S_CHUNK(2)
  AIN_WRITE(1, pv2)
  bar_lds();
  // body 3: agg slice2; chunk3 S
  AGG_SLICE(sC, 2)
  S_CHUNK(3)
  bar_lds();
  // final: agg slice3
  AGG_SLICE(sD, 3)

  // ---- store Ocrop (bf16) ----
#pragma unroll
  for (int fi = 0; fi < 4; ++fi) {
    const int f = wf0 + fi * 16 + lr;
    const int n = n0 + lg * 4;
#pragma unroll
    for (int r = 0; r < 4; ++r)
      Ocrop[((size_t)b * CN + n + r) * F + f] = f2bf(acc[fi][r]);
  }
}

// ---------------------------------------------------------------------------
// KB: BN stats + normalize crop rows (vectorized x4; bf16 in, fp32 out).
// ---------------------------------------------------------------------------
__global__ __launch_bounds__(256) void gcn_kb(
    const ushort* __restrict__ Ocrop, float* __restrict__ out,
    const float* __restrict__ gamma, const float* __restrict__ beta) {
  __shared__ f32x4 s_l[256], s2_l[256];
  __shared__ f32x4 m_l[32], r_l[32];
  const int tid = threadIdx.x;
  const int qq = tid & 31, bg = tid >> 5;
  const int j  = (blockIdx.x * 32 + qq) * 4;
  const int nl = j >> 7, f = j & 127;
  const int nf = (CROP0 + nl) * F + f;
  const ushort* p = Ocrop + (size_t)j + (size_t)bg * 8 * CN * F;

  f32x4 xv[8];
  f32x4 s = {0.f, 0.f, 0.f, 0.f}, s2 = {0.f, 0.f, 0.f, 0.f};
#pragma unroll
  for (int bb = 0; bb < 8; ++bb) {
    const ushort4 u =
        *reinterpret_cast<const ushort4*>(&p[(size_t)bb * CN * F]);
    f32x4 v;
    v[0] = bf2f(u.x); v[1] = bf2f(u.y); v[2] = bf2f(u.z); v[3] = bf2f(u.w);
    xv[bb] = v;
    s += v;
    s2 += v * v;
  }
  s_l[tid]  = s;
  s2_l[tid] = s2;
  __syncthreads();
  if (tid < 32) {
    f32x4 ts = {0.f, 0.f, 0.f, 0.f}, ts2 = {0.f, 0.f, 0.f, 0.f};
#pragma unroll
    for (int g = 0; g < 8; ++g) {
      ts += s_l[g * 32 + tid];
      ts2 += s2_l[g * 32 + tid];
    }
    const f32x4 mean = ts * (1.f / BATCH);
    const f32x4 var  = ts2 * (1.f / BATCH) - mean * mean;
    f32x4 rs;
    rs[0] = rsqrtf(var[0] + BN_EPS);
    rs[1] = rsqrtf(var[1] + BN_EPS);
    rs[2] = rsqrtf(var[2] + BN_EPS);
    rs[3] = rsqrtf(var[3] + BN_EPS);
    m_l[tid] = mean;
    r_l[tid] = rs;
  }
  __syncthreads();
  const f32x4 mean = m_l[qq];
  const f32x4 rs   = r_l[qq];
  const float4 gm = *reinterpret_cast<const float4*>(&gamma[nf]);
  const float4 bt = *reinterpret_cast<const float4*>(&beta[nf]);
  f32x4 a, c;
  a[0] = rs[0] * gm.x; a[1] = rs[1] * gm.y;
  a[2] = rs[2] * gm.z; a[3] = rs[3] * gm.w;
  c[0] = bt.x - mean[0] * a[0]; c[1] = bt.y - mean[1] * a[1];
  c[2] = bt.z - mean[2] * a[2]; c[3] = bt.w - mean[3] * a[3];
#pragma unroll
  for (int bb = 0; bb < 8; ++bb) {
    const f32x4 yv = xv[bb] * a + c;
    *reinterpret_cast<f32x4*>(
        &out[(size_t)nf + (size_t)(bg * 8 + bb) * NADJ * F]) = yv;
  }
}

extern "C" void kernel_launch(void* const* d_in, const int* in_sizes, int n_in,
                              void* d_out, int out_size, void* d_ws,
                              size_t ws_size, hipStream_t stream) {
  const float* input = (const float*)d_in[0];
  const float* adj   = (const float*)d_in[1];
  const float* W     = (const float*)d_in[2];
  const float* gamma = (const float*)d_in[3];
  const float* beta  = (const float*)d_in[4];
  float* out = (float*)d_out;

  ushort* Ocrop = (ushort*)d_ws;  // 64*256*128 bf16 = 4.2 MB

  gcn_ka<<<256, 512, 0, stream>>>(input, adj, W, beta, out, Ocrop);
  gcn_kb<<<256, 256, 0, stream>>>(Ocrop, out, gamma, beta);
}

// Round 24
// 21.651 us; speedup vs baseline: 4.8204x; 1.0032x over previous
//
#include <hip/hip_runtime.h>
#include <hip/hip_bf16.h>

#define BATCH 64
#define NADJ  512
#define F     128
#define CROP0 128
#define CROP1 384
#define CN    256
#define BN_EPS 1e-5f

typedef __attribute__((ext_vector_type(8))) short short8;
typedef __attribute__((ext_vector_type(4))) float f32x4;

__device__ __forceinline__ ushort f2bf(float x) {
  __hip_bfloat16 h = __float2bfloat16(x);  // RNE
  return *reinterpret_cast<ushort*>(&h);
}

__device__ __forceinline__ float bf2f(ushort u) {
  const unsigned v = (unsigned)u << 16;
  float f;
  __builtin_memcpy(&f, &v, 4);
  return f;
}

__device__ __forceinline__ short8 cvt8(const float4 a, const float4 b) {
  short8 r;
  r[0] = (short)f2bf(a.x); r[1] = (short)f2bf(a.y);
  r[2] = (short)f2bf(a.z); r[3] = (short)f2bf(a.w);
  r[4] = (short)f2bf(b.x); r[5] = (short)f2bf(b.y);
  r[6] = (short)f2bf(b.z); r[7] = (short)f2bf(b.w);
  return r;
}

// Relaxed barrier: publish LDS writes (lgkmcnt only) + s_barrier, WITHOUT
// the vmcnt(0) drain __syncthreads() emits — prefetches stay in flight.
__device__ __forceinline__ void bar_lds() {
  asm volatile("s_waitcnt lgkmcnt(0)" ::: "memory");
  __builtin_amdgcn_s_barrier();
  asm volatile("" ::: "memory");
}

// ---------------------------------------------------------------------------
// KA v23 (FROZEN — 6 consecutive wins): fused support+aggregate.
// 256 blocks x 512 threads, 1 block/CU; block=(b,qt), 4 blocks/batch on
// XCD (b&7). Relaxed barriers; vmcnt-aware issue order; W^T hoisted to regs.
// ---------------------------------------------------------------------------
#define IN_PREFETCH(PV, CHUNK)                                              \
  _Pragma("unroll") for (int q = 0; q < 4; ++q)                             \
      PV[q] = *reinterpret_cast<const float4*>(                             \
          &inb[(size_t)((CHUNK) * 64 + ml0 + q * 16) * F + ic4]);

#define ADJ_SLICE(SX, C)                                                    \
  _Pragma("unroll") for (int t = 0; t < 4; ++t)                             \
      SX[t] = *reinterpret_cast<const float4*>(                             \
          &a0[(C) * 64 + (t >> 1) * 32 + lg * 8 + (t & 1) * 4]);

#define AIN_WRITE(BUF, PV)                                                  \
  _Pragma("unroll") for (int q = 0; q < 4; ++q)                             \
      *reinterpret_cast<ushort4*>(&ain[BUF][ml0 + q * 16][ic4]) =           \
          make_ushort4(f2bf(PV[q].x), f2bf(PV[q].y), f2bf(PV[q].z),         \
                       f2bf(PV[q].w));

#define S_CHUNK(CC)                                                         \
  {                                                                         \
    f32x4 sacc[4] = {};                                                     \
    _Pragma("unroll") for (int ks = 0; ks < 4; ++ks) {                      \
      const int k0 = ks * 32 + lg * 8;                                      \
      const short8 av =                                                     \
          *reinterpret_cast<const short8*>(&ain[(CC) & 1][msub + lr][k0]);  \
      _Pragma("unroll") for (int fi = 0; fi < 4; ++fi) {                    \
        sacc[fi] = __builtin_amdgcn_mfma_f32_16x16x32_bf16(                 \
            av, wreg[ks * 4 + fi], sacc[fi], 0, 0, 0);                      \
      }                                                                     \
    }                                                                       \
    _Pragma("unroll") for (int fi = 0; fi < 4; ++fi)                        \
        *reinterpret_cast<ushort4*>(                                        \
            &stl[sf0 + fi * 16 + lr][(CC) * 64 + msub + lg * 4]) =          \
            make_ushort4(f2bf(sacc[fi][0]), f2bf(sacc[fi][1]),              \
                         f2bf(sacc[fi][2]), f2bf(sacc[fi][3]));             \
  }

#define AGG_SLICE(SX, C)                                                    \
  _Pragma("unroll") for (int ks2 = 0; ks2 < 2; ++ks2) {                     \
    const int k0 = (C) * 64 + ks2 * 32 + lg * 8;                            \
    const short8 av = cvt8(SX[2 * ks2], SX[2 * ks2 + 1]);                   \
    _Pragma("unroll") for (int fi = 0; fi < 4; ++fi) {                      \
      const short8 bv =                                                     \
          *reinterpret_cast<const short8*>(&stl[wf0 + fi * 16 + lr][k0]);   \
      acc[fi] = __builtin_amdgcn_mfma_f32_16x16x32_bf16(av, bv, acc[fi],    \
                                                        0, 0, 0);           \
    }                                                                       \
  }

__global__ __launch_bounds__(512, 1) void gcn_ka(
    const float* __restrict__ input, const float* __restrict__ adj,
    const float* __restrict__ W, const float* __restrict__ beta,
    float* __restrict__ out, ushort* __restrict__ Ocrop) {
  const int x = blockIdx.x & 7, y = blockIdx.x >> 3;
  const int b  = ((y >> 2) << 3) | x;  // batch
  const int qt = y & 3;                // quarter (64 n-rows)
  __shared__ ushort wt[128][136];      // W^T [f][i]
  __shared__ ushort ain[2][64][136];   // input chunk dbuf [m][i]
  __shared__ ushort stl[128][268];     // S^T full [f][m]
  const int tid = threadIdx.x;
  const int l = tid & 63, w = tid >> 6;
  const int lr = l & 15, lg = l >> 4;
  const int n0   = qt * 64 + (w & 3) * 16;
  const int wf0  = (w >> 2) * 64;
  const int msub = (w & 3) * 16;
  const int sf0  = (w >> 2) * 64;
  const int ml0  = tid >> 5;
  const int ic4  = (tid & 31) * 4;
  const float* inb = input + ((size_t)b * NADJ + CROP0) * F;
  const float* a0 =
      adj + ((size_t)b * NADJ + CROP0 + n0 + lr) * NADJ + CROP0;

  // ---- issue order: W (critical) ----
  const int i0 = tid & 63;
  const int fq = (tid >> 6) * 16;
  float4 wv[8];
#pragma unroll
  for (int ih = 0; ih < 2; ++ih) {
    const float* wr = &W[(size_t)(i0 + ih * 64) * F + fq];
#pragma unroll
    for (int q = 0; q < 4; ++q)
      wv[ih * 4 + q] = reinterpret_cast<const float4*>(wr)[q];
  }
  // ---- input chunks 0,1 ----
  float4 pv[4], pv2[4];
  IN_PREFETCH(pv, 0)
  IN_PREFETCH(pv2, 1)
  // ---- adj slices 0,1 ----
  float4 sA[4], sB[4], sC[4], sD[4];
  ADJ_SLICE(sA, 0)
  ADJ_SLICE(sB, 1)
  // ---- beta loads ----
  float4 btv[4];
  int bidx[4];
#pragma unroll
  for (int q = 0; q < 4; ++q) {
    const int g2 = blockIdx.x * 512 + tid + q * 131072;
    const int c4 = (g2 & 31) * 4;
    const int rr = (g2 >> 5) & 255;
    const int bb = g2 >> 13;
    const int n  = rr < 128 ? rr : rr + 256;
    btv[q]  = *reinterpret_cast<const float4*>(&beta[(size_t)n * F + c4]);
    bidx[q] = ((bb * NADJ + n) << 7) + c4;
  }

  // ---- wt writes (waits W only) ----
#pragma unroll
  for (int ih = 0; ih < 2; ++ih) {
    const int i = i0 + ih * 64;
#pragma unroll
    for (int q = 0; q < 4; ++q) {
      wt[fq + q * 4 + 0][i] = f2bf(wv[ih * 4 + q].x);
      wt[fq + q * 4 + 1][i] = f2bf(wv[ih * 4 + q].y);
      wt[fq + q * 4 + 2][i] = f2bf(wv[ih * 4 + q].z);
      wt[fq + q * 4 + 3][i] = f2bf(wv[ih * 4 + q].w);
    }
  }
  // ---- ain[0] writes (waits input c0 only) ----
  AIN_WRITE(0, pv)
  bar_lds();

  // ---- beta-fill stores: stream during S-phase ----
#pragma unroll
  for (int q = 0; q < 4; ++q)
    *reinterpret_cast<float4*>(&out[(size_t)bidx[q]]) = btv[q];

  // ---- hoist W^T fragments to registers ONCE ----
  short8 wreg[16];
#pragma unroll
  for (int ks = 0; ks < 4; ++ks)
#pragma unroll
    for (int fi = 0; fi < 4; ++fi)
      wreg[ks * 4 + fi] = *reinterpret_cast<const short8*>(
          &wt[sf0 + fi * 16 + lr][ks * 32 + lg * 8]);

  f32x4 acc[4] = {};
  // body 0
  ADJ_SLICE(sC, 2)
  IN_PREFETCH(pv, 2)
  S_CHUNK(0)
  AIN_WRITE(1, pv2)
  bar_lds();
  // body 1
  ADJ_SLICE(sD, 3)
  IN_PREFETCH(pv2, 3)
  AGG_SLICE(sA, 0)
  S_CHUNK(1)
  AIN_WRITE(0, pv)
  bar_lds();
  // body 2
  AGG_SLICE(sB, 1)
  S_CHUNK(2)
  AIN_WRITE(1, pv2)
  bar_lds();
  // body 3
  AGG_SLICE(sC, 2)
  S_CHUNK(3)
  bar_lds();
  // final
  AGG_SLICE(sD, 3)

  // ---- store Ocrop (bf16) ----
#pragma unroll
  for (int fi = 0; fi < 4; ++fi) {
    const int f = wf0 + fi * 16 + lr;
    const int n = n0 + lg * 4;
#pragma unroll
    for (int r = 0; r < 4; ++r)
      Ocrop[((size_t)b * CN + n + r) * F + f] = f2bf(acc[fi][r]);
  }
}

// ---------------------------------------------------------------------------
// KB v24: 512 blocks x 256 threads (2 blocks/CU, 8 waves/CU — double TLP).
// Block = 16 feature-quads (64 features); thread = (quad qq=tid&15,
// batch-group bg=tid>>4 of 4 batches). ushort4 loads, float4 stores.
// ---------------------------------------------------------------------------
__global__ __launch_bounds__(256) void gcn_kb(
    const ushort* __restrict__ Ocrop, float* __restrict__ out,
    const float* __restrict__ gamma, const float* __restrict__ beta) {
  __shared__ f32x4 s_l[256], s2_l[256];
  __shared__ f32x4 m_l[16], r_l[16];
  const int tid = threadIdx.x;
  const int qq = tid & 15, bg = tid >> 4;     // 16 quads x 16 batch-groups
  const int j  = (blockIdx.x * 16 + qq) * 4;  // feature id nl*128+f, f%4==0
  const int nl = j >> 7, f = j & 127;
  const int nf = (CROP0 + nl) * F + f;
  const ushort* p = Ocrop + (size_t)j + (size_t)bg * 4 * CN * F;

  f32x4 xv[4];
  f32x4 s = {0.f, 0.f, 0.f, 0.f}, s2 = {0.f, 0.f, 0.f, 0.f};
#pragma unroll
  for (int bb = 0; bb < 4; ++bb) {
    const ushort4 u =
        *reinterpret_cast<const ushort4*>(&p[(size_t)bb * CN * F]);
    f32x4 v;
    v[0] = bf2f(u.x); v[1] = bf2f(u.y); v[2] = bf2f(u.z); v[3] = bf2f(u.w);
    xv[bb] = v;
    s += v;
    s2 += v * v;
  }
  s_l[tid]  = s;
  s2_l[tid] = s2;
  __syncthreads();
  if (tid < 16) {
    f32x4 ts = {0.f, 0.f, 0.f, 0.f}, ts2 = {0.f, 0.f, 0.f, 0.f};
#pragma unroll
    for (int g = 0; g < 16; ++g) {
      ts += s_l[g * 16 + tid];
      ts2 += s2_l[g * 16 + tid];
    }
    const f32x4 mean = ts * (1.f / BATCH);
    const f32x4 var  = ts2 * (1.f / BATCH) - mean * mean;
    f32x4 rs;
    rs[0] = rsqrtf(var[0] + BN_EPS);
    rs[1] = rsqrtf(var[1] + BN_EPS);
    rs[2] = rsqrtf(var[2] + BN_EPS);
    rs[3] = rsqrtf(var[3] + BN_EPS);
    m_l[tid] = mean;
    r_l[tid] = rs;
  }
  __syncthreads();
  const f32x4 mean = m_l[qq];
  const f32x4 rs   = r_l[qq];
  const float4 gm = *reinterpret_cast<const float4*>(&gamma[nf]);
  const float4 bt = *reinterpret_cast<const float4*>(&beta[nf]);
  f32x4 a, c;
  a[0] = rs[0] * gm.x; a[1] = rs[1] * gm.y;
  a[2] = rs[2] * gm.z; a[3] = rs[3] * gm.w;
  c[0] = bt.x - mean[0] * a[0]; c[1] = bt.y - mean[1] * a[1];
  c[2] = bt.z - mean[2] * a[2]; c[3] = bt.w - mean[3] * a[3];
#pragma unroll
  for (int bb = 0; bb < 4; ++bb) {
    const f32x4 yv = xv[bb] * a + c;
    *reinterpret_cast<f32x4*>(
        &out[(size_t)nf + (size_t)(bg * 4 + bb) * NADJ * F]) = yv;
  }
}

extern "C" void kernel_launch(void* const* d_in, const int* in_sizes, int n_in,
                              void* d_out, int out_size, void* d_ws,
                              size_t ws_size, hipStream_t stream) {
  const float* input = (const float*)d_in[0];
  const float* adj   = (const float*)d_in[1];
  const float* W     = (const float*)d_in[2];
  const float* gamma = (const float*)d_in[3];
  const float* beta  = (const float*)d_in[4];
  float* out = (float*)d_out;

  ushort* Ocrop = (ushort*)d_ws;  // 64*256*128 bf16 = 4.2 MB

  gcn_ka<<<256, 512, 0, stream>>>(input, adj, W, beta, out, Ocrop);
  gcn_kb<<<512, 256, 0, stream>>>(Ocrop, out, gamma, beta);
}